// Round 13
// baseline (50.862 us; speedup 1.0000x reference)
//
#include <hip/hip_runtime.h>
#include <math.h>

#define NEAR_T   2.0f
#define FAR_T    6.0f
#define EPS_W_C  1e-5f
#define EPS_T_C  1e-10f
#define FAR_DIST 1e10f
#define L2E      1.4426950408889634f
#define INV63    (1.0f / 63.0f)

typedef float v2f __attribute__((ext_vector_type(2)));

__device__ __forceinline__ float tval(int i) {
    return NEAR_T + (FAR_T - NEAR_T) * ((float)i * INV63);
}
__device__ __forceinline__ float rcp_fast(float x) { return __builtin_amdgcn_rcpf(x); }
__device__ __forceinline__ float exp2_f(float x)  { return __builtin_amdgcn_exp2f(x); }
__device__ __forceinline__ float log2_f(float x)  { return __builtin_amdgcn_logf(x); }
__device__ __forceinline__ v2f fma2(v2f a, v2f b, v2f c) {
    return __builtin_elementwise_fma(a, b, c);
}
__device__ __forceinline__ float clamp30(float x) {
    return fminf(fmaxf(x, -30.0f), 30.0f);   // v_med3; exact for sigmoid in f32
}

// safe base-2 softplus (two-path log2(1+e)): preserves sigma down to ~1e-13,
// REQUIRED where dist=1e10 can saturate alpha from a tiny sigma (R2 failure).
__device__ __forceinline__ float softplus2_safe(float xp) {
    const float e = exp2_f(-fabsf(xp));
    const float big   = log2_f(1.0f + e);
    const float small = e * (1.4426950f - e * (0.72134751f - e * 0.48089835f));
    return fmaxf(xp, 0.0f) + ((e > 0.0078125f) ? big : small);
}

struct FieldV { float sig; float c2; v2f c01; };

// fast field eval. Density: softplus without the small path (flushes sigma
// < 2^-24 to 0; fine for bounded dists — FAR_DIST consumers use the safe
// version). Colors: THREE sigmoids with ONE shared rcp:
//   r = rcp((1+z0)(1+z1)(1+z2)),  sigma_k = prod_{m!=k}(1+z_m) * r
// Args clamped to +-30 (base-2): sigma saturates to exactly 1.0f/0.0f there,
// and products stay <= 2^90 — no inf/NaN path.
__device__ __forceinline__ FieldV eval_fast(float t, v2f A0, v2f A1, v2f B0, v2f B1) {
    const v2f tt = {t, t};
    const v2f a = fma2(tt, A1, A0);          // (dd', c2-arg)
    const v2f b = fma2(tt, B1, B0);          // (c0-arg, c1-arg)
    const float ea = exp2_f(-fabsf(a.x));
    const float z2 = exp2_f(-clamp30(a.y));
    const float z0 = exp2_f(-clamp30(b.x));
    const float z1 = exp2_f(-clamp30(b.y));
    const float d0 = 1.0f + z0, d1 = 1.0f + z1, d2 = 1.0f + z2;
    const float d01 = d0 * d1;
    const float r = rcp_fast(d01 * d2);
    FieldV res;
    res.sig = fmaxf(a.x, 0.0f) + log2_f(1.0f + ea);
    res.c2  = d01 * r;
    res.c01 = (v2f){(d1 * d2) * r, (d0 * d2) * r};
    return res;
}

__global__ __launch_bounds__(256)
void volrender_tpr(const float* __restrict__ ro_g,
                   const float* __restrict__ rd_g,
                   const float* __restrict__ Wd_g,
                   const float* __restrict__ Wc_g,
                   float* __restrict__ out, int N) {
    __shared__ float s_cdf[64][256];   // [i][tid]: banks = tid%32, conflict-free

    const int tid = threadIdx.x;
    const int ray = blockIdx.x * 256 + tid;
    if (ray >= N) return;

    const float ox = ro_g[ray * 3 + 0], oy = ro_g[ray * 3 + 1], oz = ro_g[ray * 3 + 2];
    const float dx = rd_g[ray * 3 + 0], dy = rd_g[ray * 3 + 1], dz = rd_g[ray * 3 + 2];
    const float wd0 = Wd_g[0], wd1 = Wd_g[1], wd2 = Wd_g[2];
    float wcm[9];
#pragma unroll
    for (int k = 0; k < 9; ++k) wcm[k] = Wc_g[k];

    // affine-in-t field coefficients, pre-scaled by log2e; packed as
    // A = (density, color2), B = (color0, color1)
    const v2f A0 = { (ox * wd0 + oy * wd1 + oz * wd2) * L2E,
                     (ox * wcm[2] + oy * wcm[5] + oz * wcm[8]) * L2E };
    const v2f A1 = { (dx * wd0 + dy * wd1 + dz * wd2) * L2E,
                     (dx * wcm[2] + dy * wcm[5] + dz * wcm[8]) * L2E };
    const v2f B0 = { (ox * wcm[0] + oy * wcm[3] + oz * wcm[6]) * L2E,
                     (ox * wcm[1] + oy * wcm[4] + oz * wcm[7]) * L2E };
    const v2f B1 = { (dx * wcm[0] + dy * wcm[3] + dz * wcm[6]) * L2E,
                     (dx * wcm[1] + dy * wcm[4] + dz * wcm[7]) * L2E };

    const float W = (FAR_T - NEAR_T) * INV63;
    const float TMAX = tval(63);

    const long Nl = N;
    float* out_rgb  = out;
    float* out_dep  = out + 3 * Nl;
    float* out_acc  = out + 4 * Nl;
    float* out_frgb = out + 5 * Nl;
    float* out_fdep = out + 8 * Nl;
    float* out_facc = out + 9 * Nl;

    // ---------------- pass 1: coarse march + cdf store ----------------
    float trans = 1.0f, acc = 0.0f, dep = 0.0f, r2 = 0.0f, total = 0.0f;
    v2f r01 = {0.0f, 0.0f};
    float t = NEAR_T;
#pragma unroll 4
    for (int i = 0; i < 63; ++i) {
        const FieldV F = eval_fast(t, A0, A1, B0, B1);
        const float a = 1.0f - exp2_f(-F.sig * W);
        const float w = a * trans;
        trans *= (1.0f - a + EPS_T_C);
        acc += w; dep = fmaf(w, t, dep);
        r01 = fma2((v2f){w, w}, F.c01, r01);
        r2 = fmaf(w, F.c2, r2);
        total += w + EPS_W_C;
        s_cdf[i][tid] = total;
        t += W;
    }
    {   // i = 63: dist = FAR_DIST -> needs safe softplus
        FieldV F = eval_fast(t, A0, A1, B0, B1);
        const float sig = softplus2_safe(fmaf(t, A1.x, A0.x));
        const float a = 1.0f - exp2_f(-sig * FAR_DIST);
        const float w = a * trans;
        acc += w; dep = fmaf(w, t, dep);
        r01 = fma2((v2f){w, w}, F.c01, r01);
        r2 = fmaf(w, F.c2, r2);
        total += w + EPS_W_C;
        s_cdf[63][tid] = total;
    }
    {
        const float bg = 1.0f - acc;
        out_rgb[ray * 3 + 0] = r01.x + bg;
        out_rgb[ray * 3 + 1] = r01.y + bg;
        out_rgb[ray * 3 + 2] = r2 + bg;
        out_dep[ray] = dep;
        out_acc[ray] = acc;
    }
    const float inv_total = rcp_fast(total);

    // ---------------- pass 2: fused sample + merge + fine ----------------
    float transf = 1.0f, facc = 0.0f, fdep = 0.0f, fr2 = 0.0f;
    v2f fr01 = {0.0f, 0.0f};
    float lo, hi, bin0, bin1, binw;
    int i, j = 0;
    float u = 0.0f;                         // = j/63, incremental
    float pt, ps, pc2;                      // lagged previous merged element
    v2f pc01;
    float Snext;

    {   // peel e=0: always grid 0
        const FieldV F = eval_fast(NEAR_T, A0, A1, B0, B1);
        ps = F.sig; pc01 = F.c01; pc2 = F.c2; pt = NEAR_T;
        lo = 0.0f;
        hi = s_cdf[0][tid] * inv_total;
        bin0 = NEAR_T; bin1 = NEAR_T + W; binw = bin1 - bin0;
        i = 1;
        Snext = s_cdf[1][tid];
    }

#pragma unroll 4
    for (int e = 1; e < 128; ++e) {
        // importance-sample candidate from head u
        float dnm = hi - lo;
        dnm = (dnm < EPS_W_C) ? 1.0f : dnm;
        const float ts = fmaf((u - lo) * rcp_fast(dnm), binw, bin0);
        const bool samp = (j < 64) && ((i >= 64) || (u < hi));
        const float tm = samp ? ts : bin1;

        const FieldV F = eval_fast(tm, A0, A1, B0, B1);

        // fine composite of PREVIOUS element with dist = tm - pt
        const float af = 1.0f - exp2_f(-ps * (tm - pt));
        const float wf = af * transf;
        transf *= (1.0f - af + EPS_T_C);
        facc += wf; fdep = fmaf(wf, pt, fdep);
        fr01 = fma2((v2f){wf, wf}, pc01, fr01);
        fr2 = fmaf(wf, pc2, fr2);

        if (samp) {
            ++j; u += INV63;
        } else {
            lo = hi;
            hi = Snext * inv_total;
            bin0 = bin1;
            bin1 = fminf(bin1 + W, TMAX);
            binw = bin1 - bin0;
            ++i;
            Snext = s_cdf[min(i, 63)][tid];
        }
        pt = tm; ps = F.sig; pc01 = F.c01; pc2 = F.c2;
    }

    {   // epilogue: last merged element gets FAR_DIST -> safe sigma recompute
        const float sig = softplus2_safe(fmaf(pt, A1.x, A0.x));
        const float af = 1.0f - exp2_f(-sig * FAR_DIST);
        const float wf = af * transf;
        facc += wf; fdep = fmaf(wf, pt, fdep);
        fr01 = fma2((v2f){wf, wf}, pc01, fr01);
        fr2 = fmaf(wf, pc2, fr2);

        const float bg = 1.0f - facc;
        out_frgb[ray * 3 + 0] = fr01.x + bg;
        out_frgb[ray * 3 + 1] = fr01.y + bg;
        out_frgb[ray * 3 + 2] = fr2 + bg;
        out_fdep[ray] = fdep;
        out_facc[ray] = facc;
    }
}

extern "C" void kernel_launch(void* const* d_in, const int* in_sizes, int n_in,
                              void* d_out, int out_size, void* d_ws, size_t ws_size,
                              hipStream_t stream) {
    const float* ro = (const float*)d_in[0];
    const float* rd = (const float*)d_in[1];
    // d_in[2] exposure_values, d_in[5] appearance_ids: unused by reference
    const float* Wd = (const float*)d_in[3];
    const float* Wc = (const float*)d_in[4];
    float* out = (float*)d_out;

    const int N = in_sizes[0] / 3;
    const int grid = (N + 255) / 256;
    volrender_tpr<<<grid, 256, 0, stream>>>(ro, rd, Wd, Wc, out, N);
}

// Round 14
// 44.432 us; speedup vs baseline: 1.1447x; 1.1447x over previous
//
#include <hip/hip_runtime.h>
#include <math.h>

#define NEAR_T   2.0f
#define FAR_T    6.0f
#define EPS_W_C  1e-5f
#define EPS_T_C  1e-10f
#define FAR_DIST 1e10f
#define L2E      1.4426950408889634f
#define INV63    (1.0f / 63.0f)

typedef float v2f __attribute__((ext_vector_type(2)));

__device__ __forceinline__ float tval(int i) {
    return NEAR_T + (FAR_T - NEAR_T) * ((float)i * INV63);
}
__device__ __forceinline__ float rcp_fast(float x) { return __builtin_amdgcn_rcpf(x); }
__device__ __forceinline__ float exp2_f(float x)  { return __builtin_amdgcn_exp2f(x); }
__device__ __forceinline__ float log2_f(float x)  { return __builtin_amdgcn_logf(x); }
__device__ __forceinline__ v2f fma2(v2f a, v2f b, v2f c) {
    return __builtin_elementwise_fma(a, b, c);
}

// safe base-2 softplus (two-path log2(1+e)): preserves sigma down to ~1e-13,
// REQUIRED where dist=1e10 can saturate alpha from a tiny sigma (R2 failure).
__device__ __forceinline__ float softplus2_safe(float xp) {
    const float e = exp2_f(-fabsf(xp));
    const float big   = log2_f(1.0f + e);
    const float small = e * (1.4426950f - e * (0.72134751f - e * 0.48089835f));
    return fmaxf(xp, 0.0f) + ((e > 0.0078125f) ? big : small);
}

struct FieldV { float sig; float c2; v2f c01; };

// fast field eval (R11 version — R13's shared-rcp variant regressed).
// Density: softplus without the small path (flushes sigma < 2^-24 to 0; fine
// for bounded dists — FAR_DIST consumers use the safe version).
__device__ __forceinline__ FieldV eval_fast(float t, v2f A0, v2f A1, v2f B0, v2f B1) {
    const v2f tt = {t, t};
    const v2f a = fma2(tt, A1, A0);          // (dd', c2-arg)
    const v2f b = fma2(tt, B1, B0);          // (c0-arg, c1-arg)
    const float ea  = exp2_f(-fabsf(a.x));
    const float ec  = exp2_f(-a.y);
    const float eb0 = exp2_f(-b.x);
    const float eb1 = exp2_f(-b.y);
    const v2f pa = (v2f){ea, ec} + (v2f){1.0f, 1.0f};
    const v2f pb = (v2f){eb0, eb1} + (v2f){1.0f, 1.0f};
    FieldV r;
    r.sig = fmaxf(a.x, 0.0f) + log2_f(pa.x);
    r.c2  = rcp_fast(pa.y);
    r.c01 = (v2f){rcp_fast(pb.x), rcp_fast(pb.y)};
    return r;
}

__global__ __launch_bounds__(256)
void volrender_tpr(const float* __restrict__ ro_g,
                   const float* __restrict__ rd_g,
                   const float* __restrict__ Wd_g,
                   const float* __restrict__ Wc_g,
                   float* __restrict__ out, int N) {
    __shared__ float s_cdf[64][256];   // [i][tid]: banks = tid%32, conflict-free

    const int tid = threadIdx.x;
    const int ray = blockIdx.x * 256 + tid;
    if (ray >= N) return;

    const float ox = ro_g[ray * 3 + 0], oy = ro_g[ray * 3 + 1], oz = ro_g[ray * 3 + 2];
    const float dx = rd_g[ray * 3 + 0], dy = rd_g[ray * 3 + 1], dz = rd_g[ray * 3 + 2];
    const float wd0 = Wd_g[0], wd1 = Wd_g[1], wd2 = Wd_g[2];
    float wcm[9];
#pragma unroll
    for (int k = 0; k < 9; ++k) wcm[k] = Wc_g[k];

    // affine-in-t field coefficients, pre-scaled by log2e; packed as
    // A = (density, color2), B = (color0, color1)
    const v2f A0 = { (ox * wd0 + oy * wd1 + oz * wd2) * L2E,
                     (ox * wcm[2] + oy * wcm[5] + oz * wcm[8]) * L2E };
    const v2f A1 = { (dx * wd0 + dy * wd1 + dz * wd2) * L2E,
                     (dx * wcm[2] + dy * wcm[5] + dz * wcm[8]) * L2E };
    const v2f B0 = { (ox * wcm[0] + oy * wcm[3] + oz * wcm[6]) * L2E,
                     (ox * wcm[1] + oy * wcm[4] + oz * wcm[7]) * L2E };
    const v2f B1 = { (dx * wcm[0] + dy * wcm[3] + dz * wcm[6]) * L2E,
                     (dx * wcm[1] + dy * wcm[4] + dz * wcm[7]) * L2E };

    const float W = (FAR_T - NEAR_T) * INV63;
    const float TMAX = tval(63);

    const long Nl = N;
    float* out_rgb  = out;
    float* out_dep  = out + 3 * Nl;
    float* out_acc  = out + 4 * Nl;
    float* out_frgb = out + 5 * Nl;
    float* out_fdep = out + 8 * Nl;
    float* out_facc = out + 9 * Nl;

    // ---------------- pass 1: coarse march + cdf store ----------------
    // optical-depth form: S = sum(sigma*d), T = exp2(-S), w = T_prev - T.
    // Differs from cumprod(1-alpha+1e-10) by ~1e-10 per step — invisible.
    float S1 = 0.0f, Tp1 = 1.0f;
    float acc = 0.0f, dep = 0.0f, r2 = 0.0f, total = 0.0f;
    v2f r01 = {0.0f, 0.0f};
    float t = NEAR_T;
#pragma unroll 4
    for (int i = 0; i < 63; ++i) {
        const FieldV F = eval_fast(t, A0, A1, B0, B1);
        S1 = fmaf(F.sig, W, S1);
        const float T = exp2_f(-S1);
        const float w = Tp1 - T;
        Tp1 = T;
        acc += w; dep = fmaf(w, t, dep);
        r01 = fma2((v2f){w, w}, F.c01, r01);
        r2 = fmaf(w, F.c2, r2);
        total += w + EPS_W_C;
        s_cdf[i][tid] = total;
        t += W;
    }
    {   // i = 63: dist = FAR_DIST -> needs safe softplus (tiny sigma preserved)
        FieldV F = eval_fast(t, A0, A1, B0, B1);
        const float sig = softplus2_safe(fmaf(t, A1.x, A0.x));
        S1 = fmaf(sig, FAR_DIST, S1);         // finite; exp2(-huge)=0 = saturation
        const float T = exp2_f(-S1);
        const float w = Tp1 - T;
        acc += w; dep = fmaf(w, t, dep);
        r01 = fma2((v2f){w, w}, F.c01, r01);
        r2 = fmaf(w, F.c2, r2);
        total += w + EPS_W_C;
        s_cdf[63][tid] = total;
    }
    {
        const float bg = 1.0f - acc;
        out_rgb[ray * 3 + 0] = r01.x + bg;
        out_rgb[ray * 3 + 1] = r01.y + bg;
        out_rgb[ray * 3 + 2] = r2 + bg;
        out_dep[ray] = dep;
        out_acc[ray] = acc;
    }
    const float inv_total = rcp_fast(total);

    // ---------------- pass 2: fused sample + merge + fine ----------------
    float Sf = 0.0f, Tpf = 1.0f;
    float facc = 0.0f, fdep = 0.0f, fr2 = 0.0f;
    v2f fr01 = {0.0f, 0.0f};
    float lo, hi, bin0, bin1, binw;
    int i, j = 0;
    float u = 0.0f;                         // = j/63, incremental
    float pt, ps, pc2;                      // lagged previous merged element
    v2f pc01;
    float Snext;

    {   // peel e=0: always grid 0
        const FieldV F = eval_fast(NEAR_T, A0, A1, B0, B1);
        ps = F.sig; pc01 = F.c01; pc2 = F.c2; pt = NEAR_T;
        lo = 0.0f;
        hi = s_cdf[0][tid] * inv_total;
        bin0 = NEAR_T; bin1 = NEAR_T + W; binw = bin1 - bin0;
        i = 1;
        Snext = s_cdf[1][tid];
    }

#pragma unroll 4
    for (int e = 1; e < 128; ++e) {
        // importance-sample candidate from head u
        float dnm = hi - lo;
        dnm = (dnm < EPS_W_C) ? 1.0f : dnm;
        const float ts = fmaf((u - lo) * rcp_fast(dnm), binw, bin0);
        const bool samp = (j < 64) && ((i >= 64) || (u < hi));
        const float tm = samp ? ts : bin1;

        const FieldV F = eval_fast(tm, A0, A1, B0, B1);

        // fine composite of PREVIOUS element, optical-depth form
        Sf = fmaf(ps, tm - pt, Sf);
        const float T = exp2_f(-Sf);
        const float wf = Tpf - T;
        Tpf = T;
        facc += wf; fdep = fmaf(wf, pt, fdep);
        fr01 = fma2((v2f){wf, wf}, pc01, fr01);
        fr2 = fmaf(wf, pc2, fr2);

        if (samp) {
            ++j; u += INV63;
        } else {
            lo = hi;
            hi = Snext * inv_total;
            bin0 = bin1;
            bin1 = fminf(bin1 + W, TMAX);
            binw = bin1 - bin0;
            ++i;
            Snext = s_cdf[min(i, 63)][tid];
        }
        pt = tm; ps = F.sig; pc01 = F.c01; pc2 = F.c2;
    }

    {   // epilogue: last merged element gets FAR_DIST -> safe sigma recompute
        const float sig = softplus2_safe(fmaf(pt, A1.x, A0.x));
        Sf = fmaf(sig, FAR_DIST, Sf);
        const float T = exp2_f(-Sf);
        const float wf = Tpf - T;
        facc += wf; fdep = fmaf(wf, pt, fdep);
        fr01 = fma2((v2f){wf, wf}, pc01, fr01);
        fr2 = fmaf(wf, pc2, fr2);

        const float bg = 1.0f - facc;
        out_frgb[ray * 3 + 0] = fr01.x + bg;
        out_frgb[ray * 3 + 1] = fr01.y + bg;
        out_frgb[ray * 3 + 2] = fr2 + bg;
        out_fdep[ray] = fdep;
        out_facc[ray] = facc;
    }
}

extern "C" void kernel_launch(void* const* d_in, const int* in_sizes, int n_in,
                              void* d_out, int out_size, void* d_ws, size_t ws_size,
                              hipStream_t stream) {
    const float* ro = (const float*)d_in[0];
    const float* rd = (const float*)d_in[1];
    // d_in[2] exposure_values, d_in[5] appearance_ids: unused by reference
    const float* Wd = (const float*)d_in[3];
    const float* Wc = (const float*)d_in[4];
    float* out = (float*)d_out;

    const int N = in_sizes[0] / 3;
    const int grid = (N + 255) / 256;
    volrender_tpr<<<grid, 256, 0, stream>>>(ro, rd, Wd, Wc, out, N);
}

// Round 15
// 42.934 us; speedup vs baseline: 1.1847x; 1.0349x over previous
//
#include <hip/hip_runtime.h>
#include <math.h>

#define NEAR_T   2.0f
#define FAR_T    6.0f
#define EPS_W_C  1e-5f
#define EPS_T_C  1e-10f
#define FAR_DIST 1e10f
#define L2E      1.4426950408889634f
#define INV63    (1.0f / 63.0f)

typedef float v2f __attribute__((ext_vector_type(2)));

__device__ __forceinline__ float tval(int i) {
    return NEAR_T + (FAR_T - NEAR_T) * ((float)i * INV63);
}
__device__ __forceinline__ float rcp_fast(float x) { return __builtin_amdgcn_rcpf(x); }
__device__ __forceinline__ float exp2_f(float x)  { return __builtin_amdgcn_exp2f(x); }
__device__ __forceinline__ float log2_f(float x)  { return __builtin_amdgcn_logf(x); }
__device__ __forceinline__ v2f fma2(v2f a, v2f b, v2f c) {
    return __builtin_elementwise_fma(a, b, c);
}

// safe base-2 softplus (two-path log2(1+e)): preserves sigma down to ~1e-13,
// REQUIRED where dist=1e10 can saturate alpha from a tiny sigma (R2 failure).
__device__ __forceinline__ float softplus2_safe(float xp) {
    const float e = exp2_f(-fabsf(xp));
    const float big   = log2_f(1.0f + e);
    const float small = e * (1.4426950f - e * (0.72134751f - e * 0.48089835f));
    return fmaxf(xp, 0.0f) + ((e > 0.0078125f) ? big : small);
}

struct FieldV { float sig; float c2; v2f c01; };

// fast field eval (pass 2; R11/R14 version — trades regressed in R12/R13).
__device__ __forceinline__ FieldV eval_fast(float t, v2f A0, v2f A1, v2f B0, v2f B1) {
    const v2f tt = {t, t};
    const v2f a = fma2(tt, A1, A0);          // (dd', c2-arg)
    const v2f b = fma2(tt, B1, B0);          // (c0-arg, c1-arg)
    const float ea  = exp2_f(-fabsf(a.x));
    const float ec  = exp2_f(-a.y);
    const float eb0 = exp2_f(-b.x);
    const float eb1 = exp2_f(-b.y);
    const v2f pa = (v2f){ea, ec} + (v2f){1.0f, 1.0f};
    const v2f pb = (v2f){eb0, eb1} + (v2f){1.0f, 1.0f};
    FieldV r;
    r.sig = fmaxf(a.x, 0.0f) + log2_f(pa.x);
    r.c2  = rcp_fast(pa.y);
    r.c01 = (v2f){rcp_fast(pb.x), rcp_fast(pb.y)};
    return r;
}

__global__ __launch_bounds__(256)
void volrender_tpr(const float* __restrict__ ro_g,
                   const float* __restrict__ rd_g,
                   const float* __restrict__ Wd_g,
                   const float* __restrict__ Wc_g,
                   float* __restrict__ out, int N) {
    __shared__ float s_cdf[64][256];   // [i][tid]: banks = tid%32, conflict-free

    const int tid = threadIdx.x;
    const int ray = blockIdx.x * 256 + tid;
    if (ray >= N) return;

    const float ox = ro_g[ray * 3 + 0], oy = ro_g[ray * 3 + 1], oz = ro_g[ray * 3 + 2];
    const float dx = rd_g[ray * 3 + 0], dy = rd_g[ray * 3 + 1], dz = rd_g[ray * 3 + 2];
    const float wd0 = Wd_g[0], wd1 = Wd_g[1], wd2 = Wd_g[2];
    float wcm[9];
#pragma unroll
    for (int k = 0; k < 9; ++k) wcm[k] = Wc_g[k];

    // affine-in-t field coefficients, pre-scaled by log2e; packed as
    // A = (density, color2), B = (color0, color1)
    const v2f A0 = { (ox * wd0 + oy * wd1 + oz * wd2) * L2E,
                     (ox * wcm[2] + oy * wcm[5] + oz * wcm[8]) * L2E };
    const v2f A1 = { (dx * wd0 + dy * wd1 + dz * wd2) * L2E,
                     (dx * wcm[2] + dy * wcm[5] + dz * wcm[8]) * L2E };
    const v2f B0 = { (ox * wcm[0] + oy * wcm[3] + oz * wcm[6]) * L2E,
                     (ox * wcm[1] + oy * wcm[4] + oz * wcm[7]) * L2E };
    const v2f B1 = { (dx * wcm[0] + dy * wcm[3] + dz * wcm[6]) * L2E,
                     (dx * wcm[1] + dy * wcm[4] + dz * wcm[7]) * L2E };

    const float W = (FAR_T - NEAR_T) * INV63;
    const float TMAX = tval(63);

    const long Nl = N;
    float* out_rgb  = out;
    float* out_dep  = out + 3 * Nl;
    float* out_acc  = out + 4 * Nl;
    float* out_frgb = out + 5 * Nl;
    float* out_fdep = out + 8 * Nl;
    float* out_facc = out + 9 * Nl;

    // ---------------- pass 1: coarse march + cdf store ----------------
    // Incremental exponentials: all 4 exp2 args are affine in t with constant
    // step W, so exp2(arg(t+W)) = exp2(arg(t)) * K with K precomputed.
    // sigma via log2(1+q), q = exp2(+arg) — identical rounding to the two-path
    // form incl. the benign flush for arg < -24 (FAR consumers use safe path).
    // Drift over 63 multiplies ~4e-6 relative — invisible.
    float q  = exp2_f(fmaf(NEAR_T, A1.x, A0.x));     // exp2(+density-arg)
    float z2 = exp2_f(-fmaf(NEAR_T, A1.y, A0.y));    // exp2(-color2-arg)
    float z0 = exp2_f(-fmaf(NEAR_T, B1.x, B0.x));
    float z1 = exp2_f(-fmaf(NEAR_T, B1.y, B0.y));
    const float Kq  = exp2_f(A1.x * W);
    const float Kz2 = exp2_f(-A1.y * W);
    const float Kz0 = exp2_f(-B1.x * W);
    const float Kz1 = exp2_f(-B1.y * W);

    // optical-depth form: S = sum(sigma*d), T = exp2(-S), w = T_prev - T.
    float S1 = 0.0f, Tp1 = 1.0f;
    float acc = 0.0f, dep = 0.0f, r2 = 0.0f, total = 0.0f;
    v2f r01 = {0.0f, 0.0f};
    float t = NEAR_T;
#pragma unroll 4
    for (int i = 0; i < 63; ++i) {
        const float sig = log2_f(1.0f + q);
        const float c0 = rcp_fast(1.0f + z0);
        const float c1 = rcp_fast(1.0f + z1);
        const float c2 = rcp_fast(1.0f + z2);
        S1 = fmaf(sig, W, S1);
        const float T = exp2_f(-S1);
        const float w = Tp1 - T;
        Tp1 = T;
        acc += w; dep = fmaf(w, t, dep);
        r01 = fma2((v2f){w, w}, (v2f){c0, c1}, r01);
        r2 = fmaf(w, c2, r2);
        total += w + EPS_W_C;
        s_cdf[i][tid] = total;
        t += W;
        q *= Kq; z0 *= Kz0; z1 *= Kz1; z2 *= Kz2;   // advance to t+W
    }
    {   // i = 63: dist = FAR_DIST -> needs safe softplus (tiny sigma preserved)
        const float sig = softplus2_safe(fmaf(t, A1.x, A0.x));
        const float c0 = rcp_fast(1.0f + z0);
        const float c1 = rcp_fast(1.0f + z1);
        const float c2 = rcp_fast(1.0f + z2);
        S1 = fmaf(sig, FAR_DIST, S1);         // finite; exp2(-huge)=0 = saturation
        const float T = exp2_f(-S1);
        const float w = Tp1 - T;
        acc += w; dep = fmaf(w, t, dep);
        r01 = fma2((v2f){w, w}, (v2f){c0, c1}, r01);
        r2 = fmaf(w, c2, r2);
        total += w + EPS_W_C;
        s_cdf[63][tid] = total;
    }
    {
        const float bg = 1.0f - acc;
        out_rgb[ray * 3 + 0] = r01.x + bg;
        out_rgb[ray * 3 + 1] = r01.y + bg;
        out_rgb[ray * 3 + 2] = r2 + bg;
        out_dep[ray] = dep;
        out_acc[ray] = acc;
    }
    const float inv_total = rcp_fast(total);

    // ---------------- pass 2: fused sample + merge + fine (R14, unchanged) ----
    float Sf = 0.0f, Tpf = 1.0f;
    float facc = 0.0f, fdep = 0.0f, fr2 = 0.0f;
    v2f fr01 = {0.0f, 0.0f};
    float lo, hi, bin0, bin1, binw;
    int i, j = 0;
    float u = 0.0f;                         // = j/63, incremental
    float pt, ps, pc2;                      // lagged previous merged element
    v2f pc01;
    float Snext;

    {   // peel e=0: always grid 0
        const FieldV F = eval_fast(NEAR_T, A0, A1, B0, B1);
        ps = F.sig; pc01 = F.c01; pc2 = F.c2; pt = NEAR_T;
        lo = 0.0f;
        hi = s_cdf[0][tid] * inv_total;
        bin0 = NEAR_T; bin1 = NEAR_T + W; binw = bin1 - bin0;
        i = 1;
        Snext = s_cdf[1][tid];
    }

#pragma unroll 4
    for (int e = 1; e < 128; ++e) {
        // importance-sample candidate from head u
        float dnm = hi - lo;
        dnm = (dnm < EPS_W_C) ? 1.0f : dnm;
        const float ts = fmaf((u - lo) * rcp_fast(dnm), binw, bin0);
        const bool samp = (j < 64) && ((i >= 64) || (u < hi));
        const float tm = samp ? ts : bin1;

        const FieldV F = eval_fast(tm, A0, A1, B0, B1);

        // fine composite of PREVIOUS element, optical-depth form
        Sf = fmaf(ps, tm - pt, Sf);
        const float T = exp2_f(-Sf);
        const float wf = Tpf - T;
        Tpf = T;
        facc += wf; fdep = fmaf(wf, pt, fdep);
        fr01 = fma2((v2f){wf, wf}, pc01, fr01);
        fr2 = fmaf(wf, pc2, fr2);

        if (samp) {
            ++j; u += INV63;
        } else {
            lo = hi;
            hi = Snext * inv_total;
            bin0 = bin1;
            bin1 = fminf(bin1 + W, TMAX);
            binw = bin1 - bin0;
            ++i;
            Snext = s_cdf[min(i, 63)][tid];
        }
        pt = tm; ps = F.sig; pc01 = F.c01; pc2 = F.c2;
    }

    {   // epilogue: last merged element gets FAR_DIST -> safe sigma recompute
        const float sig = softplus2_safe(fmaf(pt, A1.x, A0.x));
        Sf = fmaf(sig, FAR_DIST, Sf);
        const float T = exp2_f(-Sf);
        const float wf = Tpf - T;
        facc += wf; fdep = fmaf(wf, pt, fdep);
        fr01 = fma2((v2f){wf, wf}, pc01, fr01);
        fr2 = fmaf(wf, pc2, fr2);

        const float bg = 1.0f - facc;
        out_frgb[ray * 3 + 0] = fr01.x + bg;
        out_frgb[ray * 3 + 1] = fr01.y + bg;
        out_frgb[ray * 3 + 2] = fr2 + bg;
        out_fdep[ray] = fdep;
        out_facc[ray] = facc;
    }
}

extern "C" void kernel_launch(void* const* d_in, const int* in_sizes, int n_in,
                              void* d_out, int out_size, void* d_ws, size_t ws_size,
                              hipStream_t stream) {
    const float* ro = (const float*)d_in[0];
    const float* rd = (const float*)d_in[1];
    // d_in[2] exposure_values, d_in[5] appearance_ids: unused by reference
    const float* Wd = (const float*)d_in[3];
    const float* Wc = (const float*)d_in[4];
    float* out = (float*)d_out;

    const int N = in_sizes[0] / 3;
    const int grid = (N + 255) / 256;
    volrender_tpr<<<grid, 256, 0, stream>>>(ro, rd, Wd, Wc, out, N);
}